// Round 5
// baseline (51.556 us; speedup 1.0000x reference)
//
#include <hip/hip_runtime.h>

#define WL 512   // window_len (t and o dims)
#define NV 64    // n_var
#define LR 16    // low rank
#define NB 512   // batch

__device__ __forceinline__ float tanh_fast(float x) {
    // tanh(x) = 1 - 2/(exp(2x)+1); exact at +-inf saturation, ~1e-7 abs err
    float e = __expf(2.0f * x);
    return 1.0f - 2.0f / (e + 1.0f);
}

// K1: tmp[b,v,k] = sum_t tanh(g[v]*x[b,t,v]) * A[t,k]   ([b,v,k] layout)
// grid = 512 (one block per b), block = 512 threads (8 waves)
// thread: v = tid&63, t-group tg = tid>>6 owns t = tg*64 .. tg*64+63
// A rows via wave-uniform (readfirstlane) addresses -> s_load/SGPR operands.
// x-loads explicitly double-buffered in chunks of 8: 8 independent 256B/wave
// loads stay in flight under each compute chunk (2KB/wave in flight; Little's
// law needs ~0.6KB/wave at 900cy HBM latency and 16 waves/CU).
__global__ __launch_bounds__(512, 4) void k_tmp(
    const float* __restrict__ x, const float* __restrict__ gating,
    const float* __restrict__ A, float* __restrict__ tmp)
{
    __shared__ float red[8 * NV * 17];  // [tg][v][k+pad] = 34.8 KiB
    const int tid = threadIdx.x;
    const int b = blockIdx.x;

    const int v = tid & 63;
    const int tg = __builtin_amdgcn_readfirstlane(tid >> 6);
    const float g = gating[v];

    float acc[LR];
#pragma unroll
    for (int k = 0; k < LR; ++k) acc[k] = 0.f;

    const float* xb = x + (size_t)b * (WL * NV) + (size_t)tg * 64 * NV + v;
    const float* Abase = A + (size_t)tg * 64 * LR;

    float cur[8], nxt[8];
#pragma unroll
    for (int i = 0; i < 8; ++i) cur[i] = xb[i * NV];   // chunk 0 in flight

#pragma unroll
    for (int c = 0; c < 64; c += 8) {
        if (c < 56) {
#pragma unroll
            for (int i = 0; i < 8; ++i) nxt[i] = xb[(c + 8 + i) * NV];  // next chunk in flight
        }
#pragma unroll
        for (int i = 0; i < 8; ++i) {
            const float x1 = tanh_fast(g * cur[i]);
            const float* Ar = Abase + (c + i) * LR;    // wave-uniform, imm offset -> s_load
#pragma unroll
            for (int k = 0; k < LR; ++k) acc[k] = fmaf(x1, Ar[k], acc[k]);
        }
        if (c < 56) {
#pragma unroll
            for (int i = 0; i < 8; ++i) cur[i] = nxt[i];
        }
    }

    // partial write: stride 17 dwords -> 2 lanes/bank (free)
    float* rrow = &red[(tg * NV + v) * 17];
#pragma unroll
    for (int k = 0; k < LR; ++k) rrow[k] = acc[k];
    __syncthreads();

    // reduce 8 partials; p = v2*16 + k2 -> tmp[b][v2][k2], coalesced store
#pragma unroll
    for (int p = tid; p < LR * NV; p += 512) {   // 2 iterations
        const int v2 = p >> 4;
        const int k2 = p & 15;
        float s = 0.f;
#pragma unroll
        for (int t = 0; t < 8; ++t) s += red[(t * NV + v2) * 17 + k2];
        tmp[(size_t)b * (LR * NV) + p] = s;
    }
}

// K2: out[b,o,v] = x[b,o,v] + bias[o,v] + sum_k tmp[b,v,k]*B[k,o,v]
// grid = (32 b-chunks of 16) x (32 o-tiles of 16), block = 256 (4 waves)
//   -> 1024 blocks = exactly 4/CU at launch_bounds(256,4) = 16 waves/CU
// B slice in registers (64 VGPR), reused across 16 batches.
// BOTH x and the tmp row are prefetched one batch ahead — R4 prefetched only
// x and left 4 dependent L2 loads (~300cy) exposed per batch iteration.
__global__ __launch_bounds__(256, 4) void k_out(
    const float* __restrict__ x, const float* __restrict__ bias,
    const float* __restrict__ Bm, const float* __restrict__ tmp,
    float* __restrict__ out)
{
    const int tid = threadIdx.x;
    const int v = tid & 63;
    const int og = tid >> 6;
    const int o_base = blockIdx.y * 16 + og * 4;
    const int b0 = blockIdx.x * 16;

    float Breg[4][LR];
#pragma unroll
    for (int j = 0; j < 4; ++j) {
        const int o = o_base + j;
#pragma unroll
        for (int k = 0; k < LR; ++k)
            Breg[j][k] = Bm[((size_t)k * WL + o) * NV + v];  // 256B/wave, coalesced
    }
    float breg[4];
#pragma unroll
    for (int j = 0; j < 4; ++j) breg[j] = bias[(o_base + j) * NV + v];

    // prefetch batch b0: x residuals + tmp row
    float xr[4], xrn[4];
    float4 t4[4], t4n[4];
    {
        const float* xb = x + (size_t)b0 * WL * NV;
#pragma unroll
        for (int j = 0; j < 4; ++j) xr[j] = xb[(o_base + j) * NV + v];
        const float4* tb4 = (const float4*)(tmp + (size_t)b0 * (LR * NV) + v * LR);
#pragma unroll
        for (int q = 0; q < 4; ++q) t4[q] = tb4[q];
    }

    for (int bi = 0; bi < 16; ++bi) {
        const int b = b0 + bi;

        // issue next batch's loads before consuming this batch (latency hides
        // under the 64 FMAs + stores below)
        if (bi < 15) {
            const float* xbn = x + (size_t)(b + 1) * WL * NV;
#pragma unroll
            for (int j = 0; j < 4; ++j) xrn[j] = xbn[(o_base + j) * NV + v];
            const float4* tbn = (const float4*)(tmp + (size_t)(b + 1) * (LR * NV) + v * LR);
#pragma unroll
            for (int q = 0; q < 4; ++q) t4n[q] = tbn[q];
        }

        float tr[LR];
        tr[0]=t4[0].x; tr[1]=t4[0].y; tr[2]=t4[0].z; tr[3]=t4[0].w;
        tr[4]=t4[1].x; tr[5]=t4[1].y; tr[6]=t4[1].z; tr[7]=t4[1].w;
        tr[8]=t4[2].x; tr[9]=t4[2].y; tr[10]=t4[2].z; tr[11]=t4[2].w;
        tr[12]=t4[3].x; tr[13]=t4[3].y; tr[14]=t4[3].z; tr[15]=t4[3].w;

        float* ob = out + (size_t)b * WL * NV;
#pragma unroll
        for (int j = 0; j < 4; ++j) {
            float acc = breg[j];
#pragma unroll
            for (int k = 0; k < LR; ++k) acc += tr[k] * Breg[j][k];
            ob[(o_base + j) * NV + v] = xr[j] + acc;
        }

        if (bi < 15) {
#pragma unroll
            for (int j = 0; j < 4; ++j) xr[j] = xrn[j];
#pragma unroll
            for (int q = 0; q < 4; ++q) t4[q] = t4n[q];
        }
    }
}

extern "C" void kernel_launch(void* const* d_in, const int* in_sizes, int n_in,
                              void* d_out, int out_size, void* d_ws, size_t ws_size,
                              hipStream_t stream) {
    const float* x      = (const float*)d_in[0];  // [512,512,64,1]
    const float* gating = (const float*)d_in[1];  // [64]
    const float* bias   = (const float*)d_in[2];  // [512,64]
    const float* A      = (const float*)d_in[3];  // [512,16]
    const float* Bm     = (const float*)d_in[4];  // [16,512,64]
    float* out = (float*)d_out;
    float* tmp = (float*)d_ws;                    // 512*16*64 f32 = 2 MiB ([b,v,k])

    k_tmp<<<NB, 512, 0, stream>>>(x, gating, A, tmp);
    k_out<<<dim3(32, 32), 256, 0, stream>>>(x, bias, Bm, tmp, out);
}